// Round 15
// baseline (428.558 us; speedup 1.0000x reference)
//
#include <hip/hip_runtime.h>
#include <hip/hip_bf16.h>

typedef short frag8 __attribute__((ext_vector_type(8)));   // 8 bf16 (4 VGPRs) MFMA operand
typedef float facc4 __attribute__((ext_vector_type(4)));   // 4 fp32 MFMA accumulator
typedef float f32x4 __attribute__((ext_vector_type(4)));   // clang vector: ok for nontemporal builtin
typedef unsigned short ushort_t;
typedef unsigned int uint_t;

#define DEV static __device__ __forceinline__

// manual RNE fp32->bf16 (inputs finite)
DEV ushort_t f2bf(float f) {
  uint_t u = __float_as_uint(f);
  u += 0x7fffu + ((u >> 16) & 1u);
  return (ushort_t)(u >> 16);
}
// packed RNE fp32x2 -> bf16x2 (single HW instr)
DEV uint_t cvt_pk(float lo, float hi) {
  uint_t r;
  asm("v_cvt_pk_bf16_f32 %0, %1, %2" : "=v"(r) : "v"(lo), "v"(hi));
  return r;
}
DEV frag8 pack8(float4 a, float4 b) {
  union { frag8 f; uint4 u; } u_;
  u_.u.x = cvt_pk(a.x, a.y); u_.u.y = cvt_pk(a.z, a.w);
  u_.u.z = cvt_pk(b.x, b.y); u_.u.w = cvt_pk(b.z, b.w);
  return u_.f;
}
// barrier that makes LDS writes visible WITHOUT draining vmcnt (global stores keep flying)
DEV void bar_lds() { asm volatile("s_waitcnt lgkmcnt(0)\n\ts_barrier" ::: "memory"); }

constexpr int B_ = 2, S_ = 2048, H_ = 16, DM = 1280, DH = 80, DP = 96;
constexpr size_t IN_E = (size_t)B_ * S_ * DM;   // 5,242,880
constexpr size_t WT_E = (size_t)DM * DM;        // 1,638,400
// d_ws layout (bf16 element offsets), ~70 MB total.
constexpr size_t OFF_WQ = 0;
constexpr size_t OFF_WK = OFF_WQ + WT_E;
constexpr size_t OFF_WV = OFF_WK + WT_E;
constexpr size_t OFF_WD = OFF_WV + WT_E;
constexpr size_t QH_E  = (size_t)B_ * H_ * S_ * DP;   // depth padded 80->96
constexpr size_t OFF_QH = OFF_WD + WT_E;
constexpr size_t OFF_KH = OFF_QH + QH_E;
constexpr size_t VT_E  = (size_t)B_ * H_ * DH * S_;   // vh transposed [b][h][d][s]
constexpr size_t OFF_VT = OFF_KH + QH_E;
constexpr size_t OFF_OH = OFF_VT + VT_E;              // attn out, heads merged [b][s][1280] bf16

// scale folded into Q projection: (1/sqrt(80)) * log2(e)  -> logits already in log2 domain
constexpr float QSCALE = 0.16129822f;

// ---------------- convert weights fp32 -> bf16 (+ zero qh/kh depth pads) ----------------
__global__ void convert_kernel(const float* __restrict__ wq, const float* __restrict__ wk,
                               const float* __restrict__ wv, const float* __restrict__ wd,
                               ushort_t* __restrict__ ws) {
  size_t i = (size_t)blockIdx.x * blockDim.x + threadIdx.x;
  size_t stride = (size_t)gridDim.x * blockDim.x;
  constexpr size_t TOTAL = 4 * WT_E / 8;               // 819,200 chunks
  constexpr size_t NROW = (size_t)B_ * H_ * S_;        // 65,536 rows per tensor
  constexpr size_t PADC = 2 * NROW * 2;                // 2 x 8-elem pad chunks per row, qh+kh
  for (size_t c = i; c < TOTAL + PADC; c += stride) {
    if (c < TOTAL) {
      size_t e = c * 8;
      const float* s2; size_t lo;
      if      (e < WT_E)     { s2 = wq; lo = e; }
      else if (e < 2 * WT_E) { s2 = wk; lo = e - WT_E; }
      else if (e < 3 * WT_E) { s2 = wv; lo = e - 2 * WT_E; }
      else                   { s2 = wd; lo = e - 3 * WT_E; }
      float4 a = *(const float4*)(s2 + lo);
      float4 b = *(const float4*)(s2 + lo + 4);
      uint4 o;
      o.x = (uint_t)f2bf(a.x) | ((uint_t)f2bf(a.y) << 16);
      o.y = (uint_t)f2bf(a.z) | ((uint_t)f2bf(a.w) << 16);
      o.z = (uint_t)f2bf(b.x) | ((uint_t)f2bf(b.y) << 16);
      o.w = (uint_t)f2bf(b.z) | ((uint_t)f2bf(b.w) << 16);
      *(uint4*)(ws + e) = o;
    } else {
      size_t rr = c - TOTAL;
      size_t row = rr >> 1;
      size_t base = (row < NROW ? OFF_QH : OFF_KH) + (row & (NROW - 1)) * DP + DH + (rr & 1) * 8;
      uint4 z = {0u, 0u, 0u, 0u};
      *(uint4*)(ws + base) = z;
    }
  }
}

// ---------------- fused QKV projection (fp32 A staged->bf16 in regs, bf16 W) ----------------
// grid 960 = 3 projections x (32 Mtiles x 10 Ntiles). which: 0=Q(scaled),1=K,2=V(transposed out)
__global__ __launch_bounds__(256) void qkv_kernel(const float* __restrict__ Aq,
                                                  const float* __restrict__ Ak,
                                                  const float* __restrict__ Av,
                                                  const ushort_t* __restrict__ wts,
                                                  const float* __restrict__ bq,
                                                  const float* __restrict__ bk,
                                                  const float* __restrict__ bv,
                                                  ushort_t* __restrict__ qh_o,
                                                  ushort_t* __restrict__ kh_o,
                                                  ushort_t* __restrict__ vt_o) {
  __shared__ __align__(16) ushort_t sA[2][128][40];  // BK=32, padded to 40
  __shared__ __align__(16) ushort_t sB[2][128][40];
  int which = blockIdx.x / 320;
  int local = blockIdx.x - which * 320;
  int swz = (local & 7) * 40 + (local >> 3);  // XCD-chunked within each projection
  int tm = swz / 10, tn = swz % 10;
  int m0 = tm * 128, n0 = tn * 128;
  const float* A = which == 0 ? Aq : which == 1 ? Ak : Av;
  const ushort_t* W = wts + (size_t)which * WT_E;
  const float* bias = which == 0 ? bq : which == 1 ? bk : bv;
  int tid = threadIdx.x, l = tid & 63, wv = tid >> 6;
  int lm = l & 15, lg = l >> 4;
  int wr = wv >> 1, wc = wv & 1;
  int srow = tid >> 2, schk = tid & 3;
  facc4 acc[4][4] = {};
  frag8 ra[2], rb[2];

  auto load_tile = [&](int kt) {
    const float* Ab = A + (size_t)(m0 + srow) * DM + kt * 32 + schk * 8;
    ra[0] = pack8(*(const float4*)Ab, *(const float4*)(Ab + 4));
    const float* Ab2 = Ab + (size_t)64 * DM;
    ra[1] = pack8(*(const float4*)Ab2, *(const float4*)(Ab2 + 4));
    const ushort_t* Bb = W + (size_t)(n0 + srow) * DM + kt * 32 + schk * 8;
    rb[0] = *(const frag8*)Bb;
    rb[1] = *(const frag8*)(Bb + (size_t)64 * DM);
  };
  auto store_tile = [&](int bb) {
    *(frag8*)&sA[bb][srow][schk * 8] = ra[0];
    *(frag8*)&sA[bb][srow + 64][schk * 8] = ra[1];
    *(frag8*)&sB[bb][srow][schk * 8] = rb[0];
    *(frag8*)&sB[bb][srow + 64][schk * 8] = rb[1];
  };

  load_tile(0);
  store_tile(0);
  __syncthreads();
  for (int kt = 0; kt < 40; ++kt) {
    int cur = kt & 1;
    if (kt < 39) load_tile(kt + 1);
    frag8 af[4], bf[4];
#pragma unroll
    for (int i = 0; i < 4; ++i) af[i] = *(const frag8*)&sA[cur][wr * 64 + i * 16 + lm][lg * 8];
#pragma unroll
    for (int i = 0; i < 4; ++i) bf[i] = *(const frag8*)&sB[cur][wc * 64 + i * 16 + lm][lg * 8];
#pragma unroll
    for (int mi = 0; mi < 4; ++mi)
#pragma unroll
      for (int ni = 0; ni < 4; ++ni)
        acc[mi][ni] = __builtin_amdgcn_mfma_f32_16x16x32_bf16(af[mi], bf[ni], acc[mi][ni], 0, 0, 0);
    if (kt < 39) store_tile(cur ^ 1);
    __syncthreads();
  }

  float scale = (which == 0) ? QSCALE : 1.0f;
  ushort_t* dst = which == 0 ? qh_o : which == 1 ? kh_o : vt_o;
#pragma unroll
  for (int ni = 0; ni < 4; ++ni) {
    int n = n0 + wc * 64 + ni * 16 + lm;
    float bv2 = bias[n];
    int h = n / 80, d = n % 80;
#pragma unroll
    for (int mi = 0; mi < 4; ++mi) {
      int mbase = m0 + wr * 64 + mi * 16 + lg * 4;
      int b = mbase >> 11, sp = mbase & 2047;
      if (which < 2) {
#pragma unroll
        for (int r = 0; r < 4; ++r) {
          float vl = (acc[mi][ni][r] + bv2) * scale;
          dst[((size_t)(b * H_ + h) * S_ + sp + r) * DP + d] = f2bf(vl);
        }
      } else {
        uint2 u2;
        u2.x = cvt_pk(acc[mi][ni][0] + bv2, acc[mi][ni][1] + bv2);
        u2.y = cvt_pk(acc[mi][ni][2] + bv2, acc[mi][ni][3] + bv2);
        *(uint2*)&dst[((size_t)(b * H_ + h) * DH + d) * S_ + sp] = u2;
      }
    }
  }
}

// ---------------- dense output GEMM (bf16 A = attn-out, bf16 W, fp32 out) ----------------
__global__ __launch_bounds__(256) void dense_kernel(const ushort_t* __restrict__ A,
                                                    const ushort_t* __restrict__ W,
                                                    const float* __restrict__ bias,
                                                    float* __restrict__ dst_f) {
  __shared__ __align__(16) ushort_t sA[2][128][40];
  __shared__ __align__(16) ushort_t sB[2][128][40];
  int bid = blockIdx.x;
  int swz = (bid & 7) * 40 + (bid >> 3);
  int tm = swz / 10, tn = swz % 10;
  int m0 = tm * 128, n0 = tn * 128;
  int tid = threadIdx.x, l = tid & 63, wv = tid >> 6;
  int lm = l & 15, lg = l >> 4;
  int wr = wv >> 1, wc = wv & 1;
  int srow = tid >> 2, schk = tid & 3;
  facc4 acc[4][4] = {};
  frag8 ra[2], rb[2];

  auto load_tile = [&](int kt) {
    const ushort_t* Ab = A + (size_t)(m0 + srow) * DM + kt * 32 + schk * 8;
    ra[0] = *(const frag8*)Ab;
    ra[1] = *(const frag8*)(Ab + (size_t)64 * DM);
    const ushort_t* Bb = W + (size_t)(n0 + srow) * DM + kt * 32 + schk * 8;
    rb[0] = *(const frag8*)Bb;
    rb[1] = *(const frag8*)(Bb + (size_t)64 * DM);
  };
  auto store_tile = [&](int bb) {
    *(frag8*)&sA[bb][srow][schk * 8] = ra[0];
    *(frag8*)&sA[bb][srow + 64][schk * 8] = ra[1];
    *(frag8*)&sB[bb][srow][schk * 8] = rb[0];
    *(frag8*)&sB[bb][srow + 64][schk * 8] = rb[1];
  };

  load_tile(0);
  store_tile(0);
  __syncthreads();
  for (int kt = 0; kt < 40; ++kt) {
    int cur = kt & 1;
    if (kt < 39) load_tile(kt + 1);
    frag8 af[4], bf[4];
#pragma unroll
    for (int i = 0; i < 4; ++i) af[i] = *(const frag8*)&sA[cur][wr * 64 + i * 16 + lm][lg * 8];
#pragma unroll
    for (int i = 0; i < 4; ++i) bf[i] = *(const frag8*)&sB[cur][wc * 64 + i * 16 + lm][lg * 8];
#pragma unroll
    for (int mi = 0; mi < 4; ++mi)
#pragma unroll
      for (int ni = 0; ni < 4; ++ni)
        acc[mi][ni] = __builtin_amdgcn_mfma_f32_16x16x32_bf16(af[mi], bf[ni], acc[mi][ni], 0, 0, 0);
    if (kt < 39) store_tile(cur ^ 1);
    __syncthreads();
  }

#pragma unroll
  for (int ni = 0; ni < 4; ++ni) {
    int n = n0 + wc * 64 + ni * 16 + lm;
    float bv2 = bias[n];
#pragma unroll
    for (int mi = 0; mi < 4; ++mi) {
      int mbase = m0 + wr * 64 + mi * 16 + lg * 4;
#pragma unroll
      for (int r = 0; r < 4; ++r)
        __builtin_nontemporal_store(acc[mi][ni][r] + bv2, dst_f + (size_t)(mbase + r) * DM + n);
    }
  }
}

// ---------------- fused causal attention (r11 base; V direct-from-global -> 3 blocks/CU) ----
// Grid 512 x 512 threads (8 waves x 16 q = 128-q strip). Swapped QK^T: mfma(K,Q) ->
// C col = q (lane&15), row = k. K tiles of 64, depth padded 96. V read direct from
// global in PV (L2-resident ~320 KB/head, XCD-chunked swizzle) — drops the 21.8 KB
// V LDS dbuf so LDS = 43 KB -> 3 blocks/CU; launch_bounds(512,6) caps VGPR at 85 for
// 24 waves/CU (6/SIMD) of latency-hiding TLP. 2-deep K prefetch; lgkmcnt-only barriers.
// Zero-fill at the END (r11: leading stores stall sweep 1's K loads via in-order vmcnt).
__global__ __launch_bounds__(512, 6) void attn_kernel(const ushort_t* __restrict__ qh,
                                                      const ushort_t* __restrict__ kh,
                                                      const ushort_t* __restrict__ vt,
                                                      ushort_t* __restrict__ outh,
                                                      float* __restrict__ out_attn) {
  __shared__ __align__(16) ushort_t sK[2][64][104];  // 26.6 KB, 208B row stride (2-way, free)
  __shared__ __align__(16) char sP[8 * 2048];        // per-wave P tile [16 q][64 k] bf16, XOR-swizzled
  int bid = blockIdx.x;
  int half = bid >> 8, rr0 = bid & 255;
  int swz = (rr0 & 7) * 32 + (rr0 >> 3);             // XCD chunking: 4 heads per XCD
  int bh = swz >> 3, pr = swz & 7;
  int b = bh >> 4, h = bh & 15;
  int s = half ? (15 - pr) : pr;
  int tid = threadIdx.x, w = tid >> 6, l = tid & 63, lm = l & 15, lg = l >> 4;
  const ushort_t* qhb = qh + (size_t)bh * S_ * DP;
  const ushort_t* khb = kh + (size_t)bh * S_ * DP;
  const ushort_t* vtb = vt + (size_t)bh * DH * S_;
  float* attnb = out_attn + (size_t)bh * S_ * S_;
  char* Pw = sP + w * 2048;

  // K staging: 512 thr x 3 x 8B = 64 rows x 192B
  int sr[3], sc[3];
#pragma unroll
  for (int i = 0; i < 3; ++i) {
    int c = tid * 3 + i;
    sr[i] = c / 24; sc[i] = (c % 24) * 4;
  }
  uint2 stk[3];
  auto ldtK = [&](int t) {
#pragma unroll
    for (int i = 0; i < 3; ++i)
      stk[i] = *(const uint2*)(khb + (size_t)(t * 64 + sr[i]) * DP + sc[i]);
  };
  auto sttK = [&](int bb) {
#pragma unroll
    for (int i = 0; i < 3; ++i)
      *(uint2*)&sK[bb][sr[i]][sc[i]] = stk[i];
  };

  int q0 = s * 128;
  int wq0 = q0 + w * 16;      // wave's minimum q row
  int qg = wq0 + lm;          // this lane's q column

  frag8 qf[3];
#pragma unroll
  for (int kd = 0; kd < 3; ++kd)
    qf[kd] = *(const frag8*)(qhb + (size_t)qg * DP + kd * 32 + lg * 8);
  int NT = 2 * (s + 1);

  // -------- sweep 1: row sums of exp2(logit2) (K only) --------
  float rs4[4] = {0.f, 0.f, 0.f, 0.f};
  ldtK(0); sttK(0);
  if (NT > 1) ldtK(1);
  bar_lds();
  for (int t = 0; t < NT; ++t) {
    int cur = t & 1;
    if (t + 1 < NT) sttK(cur ^ 1);
    if (t + 2 < NT) ldtK(t + 2);
    if (64 * t < wq0 + 16) {                // wave not fully masked
      facc4 acc[4] = {};
#pragma unroll
      for (int mi = 0; mi < 4; ++mi)
#pragma unroll
        for (int kd = 0; kd < 3; ++kd) {
          frag8 af = *(const frag8*)((const char*)sK + cur * (64 * 104 * 2) +
                                     (mi * 16 + lm) * 208 + kd * 64 + lg * 16);
          acc[mi] = __builtin_amdgcn_mfma_f32_16x16x32_bf16(af, qf[kd], acc[mi], 0, 0, 0);
        }
      if (64 * t + 63 <= wq0) {             // fully unmasked
#pragma unroll
        for (int mi = 0; mi < 4; ++mi)
#pragma unroll
          for (int r = 0; r < 4; ++r) rs4[r] += exp2f(acc[mi][r]);
      } else {
#pragma unroll
        for (int mi = 0; mi < 4; ++mi)
#pragma unroll
          for (int r = 0; r < 4; ++r) {
            int kg = t * 64 + mi * 16 + lg * 4 + r;
            if (kg <= qg) rs4[r] += exp2f(acc[mi][r]);
          }
      }
    }
    bar_lds();
  }
  float rs = (rs4[0] + rs4[1]) + (rs4[2] + rs4[3]);
  rs += __shfl_xor(rs, 16);
  rs += __shfl_xor(rs, 32);
  float li = -__log2f(rs);                  // p = exp2(logit2 + li)

  // -------- sweep 2: recompute, write normalized attn, accumulate PV --------
  facc4 acc2[5] = {};
  ldtK(0); sttK(0);
  if (NT > 1) ldtK(1);
  bar_lds();
  for (int t = 0; t < NT; ++t) {
    int cur = t & 1;
    if (t + 1 < NT) sttK(cur ^ 1);
    if (t + 2 < NT) ldtK(t + 2);
    if (64 * t >= wq0 + 16) {               // wave fully masked: zeros
      f32x4 z = {0.f, 0.f, 0.f, 0.f};
#pragma unroll
      for (int mi = 0; mi < 4; ++mi)
        *(f32x4*)(attnb + (size_t)qg * S_ + t * 64 + mi * 16 + lg * 4) = z;
    } else {
      facc4 acc[4] = {};
#pragma unroll
      for (int mi = 0; mi < 4; ++mi)
#pragma unroll
        for (int kd = 0; kd < 3; ++kd) {
          frag8 af = *(const frag8*)((const char*)sK + cur * (64 * 104 * 2) +
                                     (mi * 16 + lm) * 208 + kd * 64 + lg * 16);
          acc[mi] = __builtin_amdgcn_mfma_f32_16x16x32_bf16(af, qf[kd], acc[mi], 0, 0, 0);
        }
      bool full = (64 * t + 63 <= wq0);
#pragma unroll
      for (int mi = 0; mi < 4; ++mi) {
        float p[4];
        if (full) {
#pragma unroll
          for (int r = 0; r < 4; ++r) p[r] = exp2f(acc[mi][r] + li);
        } else {
#pragma unroll
          for (int r = 0; r < 4; ++r) {
            int kg = t * 64 + mi * 16 + lg * 4 + r;
            p[r] = (kg <= qg) ? exp2f(acc[mi][r] + li) : 0.f;
          }
        }
        f32x4 f4 = {p[0], p[1], p[2], p[3]};
        *(f32x4*)(attnb + (size_t)qg * S_ + t * 64 + mi * 16 + lg * 4) = f4;
        uint2 pk;
        pk.x = cvt_pk(p[0], p[1]);
        pk.y = cvt_pk(p[2], p[3]);
        int kb = mi * 32 + lg * 8;
        *(uint2*)(Pw + lm * 128 + (kb ^ ((lm & 7) << 4))) = pk;  // wave-private, no barrier
      }
      // PV: P from wave-private LDS, V direct from global (L2-resident)
#pragma unroll
      for (int ks = 0; ks < 2; ++ks) {
        int kbyte = ks * 64 + lg * 16;
        frag8 pa = *(const frag8*)(Pw + lm * 128 + (kbyte ^ ((lm & 7) << 4)));
#pragma unroll
        for (int nf = 0; nf < 5; ++nf) {
          frag8 vb = *(const frag8*)(vtb + (size_t)(nf * 16 + lm) * S_ + t * 64 + ks * 32 + lg * 8);
          acc2[nf] = __builtin_amdgcn_mfma_f32_16x16x32_bf16(pa, vb, acc2[nf], 0, 0, 0);
        }
      }
    }
    bar_lds();
  }
  // PV out: D col = d (lane&15), row = q_local = lg*4 + r
#pragma unroll
  for (int nf = 0; nf < 5; ++nf)
#pragma unroll
    for (int r = 0; r < 4; ++r) {
      int qrow = q0 + w * 16 + lg * 4 + r;
      int col = h * DH + nf * 16 + lm;
      outh[((size_t)b * S_ + qrow) * DM + col] = f2bf(acc2[nf][r]);
    }

  // -------- zero-fill strictly-masked column range [128*(s+1), 2048) — at the END --------
  if (s < 15) {
    int c0 = (s + 1) * 128;
    int r2 = tid >> 2;
    int l4 = (tid & 3) << 2;
    float* rowp = attnb + (size_t)(q0 + r2) * S_ + c0 + l4;
    f32x4 z = {0.f, 0.f, 0.f, 0.f};
    for (int cc = 0; cc < 2048 - c0; cc += 16)
      __builtin_nontemporal_store(z, (f32x4*)(rowp + cc));
  }
}

extern "C" void kernel_launch(void* const* d_in, const int* in_sizes, int n_in,
                              void* d_out, int out_size, void* d_ws, size_t ws_size,
                              hipStream_t stream) {
  const float* v  = (const float*)d_in[0];
  const float* k  = (const float*)d_in[1];
  const float* q  = (const float*)d_in[2];
  // d_in[3] = mask (exact causal triu) — applied analytically
  const float* wq = (const float*)d_in[4];
  const float* bq = (const float*)d_in[5];
  const float* wk = (const float*)d_in[6];
  const float* bk = (const float*)d_in[7];
  const float* wv = (const float*)d_in[8];
  const float* bv = (const float*)d_in[9];
  const float* wd = (const float*)d_in[10];
  const float* bd = (const float*)d_in[11];
  ushort_t* ws = (ushort_t*)d_ws;
  float* out  = (float*)d_out;            // [2,2048,1280] fp32
  float* attn = out + IN_E;               // [2,16,2048,2048] fp32

  convert_kernel<<<2048, 256, 0, stream>>>(wq, wk, wv, wd, ws);
  qkv_kernel<<<960, 256, 0, stream>>>(q, k, v, ws + OFF_WQ, bq, bk, bv,
                                      ws + OFF_QH, ws + OFF_KH, ws + OFF_VT);
  attn_kernel<<<512, 512, 0, stream>>>(ws + OFF_QH, ws + OFF_KH, ws + OFF_VT, ws + OFF_OH, attn);
  dense_kernel<<<320, 256, 0, stream>>>(ws + OFF_OH, ws + OFF_WD, bd, out);
}

// Round 16
// 317.194 us; speedup vs baseline: 1.3511x; 1.3511x over previous
//
#include <hip/hip_runtime.h>
#include <hip/hip_bf16.h>

typedef short frag8 __attribute__((ext_vector_type(8)));   // 8 bf16 (4 VGPRs) MFMA operand
typedef float facc4 __attribute__((ext_vector_type(4)));   // 4 fp32 MFMA accumulator
typedef float f32x4 __attribute__((ext_vector_type(4)));   // clang vector: ok for nontemporal builtin
typedef unsigned short ushort_t;
typedef unsigned int uint_t;

#define DEV static __device__ __forceinline__

// manual RNE fp32->bf16 (inputs finite)
DEV ushort_t f2bf(float f) {
  uint_t u = __float_as_uint(f);
  u += 0x7fffu + ((u >> 16) & 1u);
  return (ushort_t)(u >> 16);
}
// packed RNE fp32x2 -> bf16x2 (single HW instr)
DEV uint_t cvt_pk(float lo, float hi) {
  uint_t r;
  asm("v_cvt_pk_bf16_f32 %0, %1, %2" : "=v"(r) : "v"(lo), "v"(hi));
  return r;
}
DEV frag8 pack8(float4 a, float4 b) {
  union { frag8 f; uint4 u; } u_;
  u_.u.x = cvt_pk(a.x, a.y); u_.u.y = cvt_pk(a.z, a.w);
  u_.u.z = cvt_pk(b.x, b.y); u_.u.w = cvt_pk(b.z, b.w);
  return u_.f;
}
// barrier that makes LDS writes visible WITHOUT draining vmcnt (global stores keep flying)
DEV void bar_lds() { asm volatile("s_waitcnt lgkmcnt(0)\n\ts_barrier" ::: "memory"); }

constexpr int B_ = 2, S_ = 2048, H_ = 16, DM = 1280, DH = 80, DP = 96;
constexpr size_t IN_E = (size_t)B_ * S_ * DM;   // 5,242,880
constexpr size_t WT_E = (size_t)DM * DM;        // 1,638,400
// d_ws layout (bf16 element offsets), ~70 MB total.
constexpr size_t OFF_WQ = 0;
constexpr size_t OFF_WK = OFF_WQ + WT_E;
constexpr size_t OFF_WV = OFF_WK + WT_E;
constexpr size_t OFF_WD = OFF_WV + WT_E;
constexpr size_t QH_E  = (size_t)B_ * H_ * S_ * DP;   // depth padded 80->96
constexpr size_t OFF_QH = OFF_WD + WT_E;
constexpr size_t OFF_KH = OFF_QH + QH_E;
constexpr size_t VT_E  = (size_t)B_ * H_ * DH * S_;   // vh transposed [b][h][d][s]
constexpr size_t OFF_VT = OFF_KH + QH_E;
constexpr size_t OFF_OH = OFF_VT + VT_E;              // attn out, heads merged [b][s][1280] bf16

// scale folded into Q projection: (1/sqrt(80)) * log2(e)  -> logits already in log2 domain
constexpr float QSCALE = 0.16129822f;

// ---------------- convert weights fp32 -> bf16 (+ zero qh/kh depth pads) ----------------
__global__ void convert_kernel(const float* __restrict__ wq, const float* __restrict__ wk,
                               const float* __restrict__ wv, const float* __restrict__ wd,
                               ushort_t* __restrict__ ws) {
  size_t i = (size_t)blockIdx.x * blockDim.x + threadIdx.x;
  size_t stride = (size_t)gridDim.x * blockDim.x;
  constexpr size_t TOTAL = 4 * WT_E / 8;               // 819,200 chunks
  constexpr size_t NROW = (size_t)B_ * H_ * S_;        // 65,536 rows per tensor
  constexpr size_t PADC = 2 * NROW * 2;                // 2 x 8-elem pad chunks per row, qh+kh
  for (size_t c = i; c < TOTAL + PADC; c += stride) {
    if (c < TOTAL) {
      size_t e = c * 8;
      const float* s2; size_t lo;
      if      (e < WT_E)     { s2 = wq; lo = e; }
      else if (e < 2 * WT_E) { s2 = wk; lo = e - WT_E; }
      else if (e < 3 * WT_E) { s2 = wv; lo = e - 2 * WT_E; }
      else                   { s2 = wd; lo = e - 3 * WT_E; }
      float4 a = *(const float4*)(s2 + lo);
      float4 b = *(const float4*)(s2 + lo + 4);
      uint4 o;
      o.x = (uint_t)f2bf(a.x) | ((uint_t)f2bf(a.y) << 16);
      o.y = (uint_t)f2bf(a.z) | ((uint_t)f2bf(a.w) << 16);
      o.z = (uint_t)f2bf(b.x) | ((uint_t)f2bf(b.y) << 16);
      o.w = (uint_t)f2bf(b.z) | ((uint_t)f2bf(b.w) << 16);
      *(uint4*)(ws + e) = o;
    } else {
      size_t rr = c - TOTAL;
      size_t row = rr >> 1;
      size_t base = (row < NROW ? OFF_QH : OFF_KH) + (row & (NROW - 1)) * DP + DH + (rr & 1) * 8;
      uint4 z = {0u, 0u, 0u, 0u};
      *(uint4*)(ws + base) = z;
    }
  }
}

// ---------------- fused QKV projection (fp32 A staged->bf16 in regs, bf16 W) ----------------
// grid 960 = 3 projections x (32 Mtiles x 10 Ntiles). which: 0=Q(scaled),1=K,2=V(transposed out)
__global__ __launch_bounds__(256) void qkv_kernel(const float* __restrict__ Aq,
                                                  const float* __restrict__ Ak,
                                                  const float* __restrict__ Av,
                                                  const ushort_t* __restrict__ wts,
                                                  const float* __restrict__ bq,
                                                  const float* __restrict__ bk,
                                                  const float* __restrict__ bv,
                                                  ushort_t* __restrict__ qh_o,
                                                  ushort_t* __restrict__ kh_o,
                                                  ushort_t* __restrict__ vt_o) {
  __shared__ __align__(16) ushort_t sA[2][128][40];  // BK=32, padded to 40
  __shared__ __align__(16) ushort_t sB[2][128][40];
  int which = blockIdx.x / 320;
  int local = blockIdx.x - which * 320;
  int swz = (local & 7) * 40 + (local >> 3);  // XCD-chunked within each projection
  int tm = swz / 10, tn = swz % 10;
  int m0 = tm * 128, n0 = tn * 128;
  const float* A = which == 0 ? Aq : which == 1 ? Ak : Av;
  const ushort_t* W = wts + (size_t)which * WT_E;
  const float* bias = which == 0 ? bq : which == 1 ? bk : bv;
  int tid = threadIdx.x, l = tid & 63, wv = tid >> 6;
  int lm = l & 15, lg = l >> 4;
  int wr = wv >> 1, wc = wv & 1;
  int srow = tid >> 2, schk = tid & 3;
  facc4 acc[4][4] = {};
  frag8 ra[2], rb[2];

  auto load_tile = [&](int kt) {
    const float* Ab = A + (size_t)(m0 + srow) * DM + kt * 32 + schk * 8;
    ra[0] = pack8(*(const float4*)Ab, *(const float4*)(Ab + 4));
    const float* Ab2 = Ab + (size_t)64 * DM;
    ra[1] = pack8(*(const float4*)Ab2, *(const float4*)(Ab2 + 4));
    const ushort_t* Bb = W + (size_t)(n0 + srow) * DM + kt * 32 + schk * 8;
    rb[0] = *(const frag8*)Bb;
    rb[1] = *(const frag8*)(Bb + (size_t)64 * DM);
  };
  auto store_tile = [&](int bb) {
    *(frag8*)&sA[bb][srow][schk * 8] = ra[0];
    *(frag8*)&sA[bb][srow + 64][schk * 8] = ra[1];
    *(frag8*)&sB[bb][srow][schk * 8] = rb[0];
    *(frag8*)&sB[bb][srow + 64][schk * 8] = rb[1];
  };

  load_tile(0);
  store_tile(0);
  __syncthreads();
  for (int kt = 0; kt < 40; ++kt) {
    int cur = kt & 1;
    if (kt < 39) load_tile(kt + 1);
    frag8 af[4], bf[4];
#pragma unroll
    for (int i = 0; i < 4; ++i) af[i] = *(const frag8*)&sA[cur][wr * 64 + i * 16 + lm][lg * 8];
#pragma unroll
    for (int i = 0; i < 4; ++i) bf[i] = *(const frag8*)&sB[cur][wc * 64 + i * 16 + lm][lg * 8];
#pragma unroll
    for (int mi = 0; mi < 4; ++mi)
#pragma unroll
      for (int ni = 0; ni < 4; ++ni)
        acc[mi][ni] = __builtin_amdgcn_mfma_f32_16x16x32_bf16(af[mi], bf[ni], acc[mi][ni], 0, 0, 0);
    if (kt < 39) store_tile(cur ^ 1);
    __syncthreads();
  }

  float scale = (which == 0) ? QSCALE : 1.0f;
  ushort_t* dst = which == 0 ? qh_o : which == 1 ? kh_o : vt_o;
#pragma unroll
  for (int ni = 0; ni < 4; ++ni) {
    int n = n0 + wc * 64 + ni * 16 + lm;
    float bv2 = bias[n];
    int h = n / 80, d = n % 80;
#pragma unroll
    for (int mi = 0; mi < 4; ++mi) {
      int mbase = m0 + wr * 64 + mi * 16 + lg * 4;
      int b = mbase >> 11, sp = mbase & 2047;
      if (which < 2) {
#pragma unroll
        for (int r = 0; r < 4; ++r) {
          float vl = (acc[mi][ni][r] + bv2) * scale;
          dst[((size_t)(b * H_ + h) * S_ + sp + r) * DP + d] = f2bf(vl);
        }
      } else {
        uint2 u2;
        u2.x = cvt_pk(acc[mi][ni][0] + bv2, acc[mi][ni][1] + bv2);
        u2.y = cvt_pk(acc[mi][ni][2] + bv2, acc[mi][ni][3] + bv2);
        *(uint2*)&dst[((size_t)(b * H_ + h) * DH + d) * S_ + sp] = u2;
      }
    }
  }
}

// ---------------- dense output GEMM (bf16 A = attn-out, bf16 W, fp32 out) ----------------
__global__ __launch_bounds__(256) void dense_kernel(const ushort_t* __restrict__ A,
                                                    const ushort_t* __restrict__ W,
                                                    const float* __restrict__ bias,
                                                    float* __restrict__ dst_f) {
  __shared__ __align__(16) ushort_t sA[2][128][40];
  __shared__ __align__(16) ushort_t sB[2][128][40];
  int bid = blockIdx.x;
  int swz = (bid & 7) * 40 + (bid >> 3);
  int tm = swz / 10, tn = swz % 10;
  int m0 = tm * 128, n0 = tn * 128;
  int tid = threadIdx.x, l = tid & 63, wv = tid >> 6;
  int lm = l & 15, lg = l >> 4;
  int wr = wv >> 1, wc = wv & 1;
  int srow = tid >> 2, schk = tid & 3;
  facc4 acc[4][4] = {};
  frag8 ra[2], rb[2];

  auto load_tile = [&](int kt) {
    const ushort_t* Ab = A + (size_t)(m0 + srow) * DM + kt * 32 + schk * 8;
    ra[0] = *(const frag8*)Ab;
    ra[1] = *(const frag8*)(Ab + (size_t)64 * DM);
    const ushort_t* Bb = W + (size_t)(n0 + srow) * DM + kt * 32 + schk * 8;
    rb[0] = *(const frag8*)Bb;
    rb[1] = *(const frag8*)(Bb + (size_t)64 * DM);
  };
  auto store_tile = [&](int bb) {
    *(frag8*)&sA[bb][srow][schk * 8] = ra[0];
    *(frag8*)&sA[bb][srow + 64][schk * 8] = ra[1];
    *(frag8*)&sB[bb][srow][schk * 8] = rb[0];
    *(frag8*)&sB[bb][srow + 64][schk * 8] = rb[1];
  };

  load_tile(0);
  store_tile(0);
  __syncthreads();
  for (int kt = 0; kt < 40; ++kt) {
    int cur = kt & 1;
    if (kt < 39) load_tile(kt + 1);
    frag8 af[4], bf[4];
#pragma unroll
    for (int i = 0; i < 4; ++i) af[i] = *(const frag8*)&sA[cur][wr * 64 + i * 16 + lm][lg * 8];
#pragma unroll
    for (int i = 0; i < 4; ++i) bf[i] = *(const frag8*)&sB[cur][wc * 64 + i * 16 + lm][lg * 8];
#pragma unroll
    for (int mi = 0; mi < 4; ++mi)
#pragma unroll
      for (int ni = 0; ni < 4; ++ni)
        acc[mi][ni] = __builtin_amdgcn_mfma_f32_16x16x32_bf16(af[mi], bf[ni], acc[mi][ni], 0, 0, 0);
    if (kt < 39) store_tile(cur ^ 1);
    __syncthreads();
  }

#pragma unroll
  for (int ni = 0; ni < 4; ++ni) {
    int n = n0 + wc * 64 + ni * 16 + lm;
    float bv2 = bias[n];
#pragma unroll
    for (int mi = 0; mi < 4; ++mi) {
      int mbase = m0 + wr * 64 + mi * 16 + lg * 4;
#pragma unroll
      for (int r = 0; r < 4; ++r)
        __builtin_nontemporal_store(acc[mi][ni][r] + bv2, dst_f + (size_t)(mbase + r) * DM + n);
    }
  }
}

// ---------------- fused causal attention (r11 structure — best known, 320 µs) ----------
// Grid 512 x 512 threads (8 waves x 16 q = 128-q strip). Swapped QK^T: mfma(K,Q) ->
// C col = q (lane&15), row = k. K tiles of 64, depth padded 96. V staged in LDS (dbuf).
// 2-deep prefetch; lgkmcnt-only barriers. Zero-fill at the END (in-order vmcnt: leading
// stores would stall sweep 1's first K loads behind ~268 MB of HBM store acks).
__global__ __launch_bounds__(512, 4) void attn_kernel(const ushort_t* __restrict__ qh,
                                                      const ushort_t* __restrict__ kh,
                                                      const ushort_t* __restrict__ vt,
                                                      ushort_t* __restrict__ outh,
                                                      float* __restrict__ out_attn) {
  __shared__ __align__(16) ushort_t sK[2][64][104];  // 26.6 KB, 208B row stride (2-way, free)
  __shared__ __align__(16) ushort_t sV[2][80][68];   // 21.8 KB, 136B row stride
  __shared__ __align__(16) char sP[8 * 2048];        // per-wave P tile [16 q][64 k] bf16, XOR-swizzled
  int bid = blockIdx.x;
  int half = bid >> 8, rr0 = bid & 255;
  int swz = (rr0 & 7) * 32 + (rr0 >> 3);             // XCD chunking: 4 heads per XCD
  int bh = swz >> 3, pr = swz & 7;
  int b = bh >> 4, h = bh & 15;
  int s = half ? (15 - pr) : pr;
  int tid = threadIdx.x, w = tid >> 6, l = tid & 63, lm = l & 15, lg = l >> 4;
  const ushort_t* qhb = qh + (size_t)bh * S_ * DP;
  const ushort_t* khb = kh + (size_t)bh * S_ * DP;
  const ushort_t* vtb = vt + (size_t)bh * DH * S_;
  float* attnb = out_attn + (size_t)bh * S_ * S_;
  char* Pw = sP + w * 2048;

  // K staging: 512 thr x 3 x 8B = 64 rows x 192B
  int sr[3], sc[3];
#pragma unroll
  for (int i = 0; i < 3; ++i) {
    int c = tid * 3 + i;
    sr[i] = c / 24; sc[i] = (c % 24) * 4;
  }
  uint2 stk[3];
  auto ldtK = [&](int t) {
#pragma unroll
    for (int i = 0; i < 3; ++i)
      stk[i] = *(const uint2*)(khb + (size_t)(t * 64 + sr[i]) * DP + sc[i]);
  };
  auto sttK = [&](int bb) {
#pragma unroll
    for (int i = 0; i < 3; ++i)
      *(uint2*)&sK[bb][sr[i]][sc[i]] = stk[i];
  };
  // V staging: 640 chunks of 16B (80 rows x 8). thread tid -> chunk tid; tid<128 also chunk 512+tid
  int vrow = tid >> 3, vcol = (tid & 7) * 8;
  uint4 stv0, stv1;
  auto ldtV = [&](int t) {
    stv0 = *(const uint4*)(vtb + (size_t)vrow * S_ + t * 64 + vcol);
    if (tid < 128) stv1 = *(const uint4*)(vtb + (size_t)(64 + vrow) * S_ + t * 64 + vcol);
  };
  auto sttV = [&](int bb) {
    *(uint4*)&sV[bb][vrow][vcol] = stv0;
    if (tid < 128) *(uint4*)&sV[bb][64 + vrow][vcol] = stv1;
  };

  int q0 = s * 128;
  int wq0 = q0 + w * 16;      // wave's minimum q row
  int qg = wq0 + lm;          // this lane's q column

  frag8 qf[3];
#pragma unroll
  for (int kd = 0; kd < 3; ++kd)
    qf[kd] = *(const frag8*)(qhb + (size_t)qg * DP + kd * 32 + lg * 8);
  int NT = 2 * (s + 1);

  // -------- sweep 1: row sums of exp2(logit2) (K only) --------
  float rs4[4] = {0.f, 0.f, 0.f, 0.f};
  ldtK(0); sttK(0);
  if (NT > 1) ldtK(1);
  bar_lds();
  for (int t = 0; t < NT; ++t) {
    int cur = t & 1;
    if (t + 1 < NT) sttK(cur ^ 1);
    if (t + 2 < NT) ldtK(t + 2);
    if (64 * t < wq0 + 16) {                // wave not fully masked
      facc4 acc[4] = {};
#pragma unroll
      for (int mi = 0; mi < 4; ++mi)
#pragma unroll
        for (int kd = 0; kd < 3; ++kd) {
          frag8 af = *(const frag8*)((const char*)sK + cur * (64 * 104 * 2) +
                                     (mi * 16 + lm) * 208 + kd * 64 + lg * 16);
          acc[mi] = __builtin_amdgcn_mfma_f32_16x16x32_bf16(af, qf[kd], acc[mi], 0, 0, 0);
        }
      if (64 * t + 63 <= wq0) {             // fully unmasked
#pragma unroll
        for (int mi = 0; mi < 4; ++mi)
#pragma unroll
          for (int r = 0; r < 4; ++r) rs4[r] += exp2f(acc[mi][r]);
      } else {
#pragma unroll
        for (int mi = 0; mi < 4; ++mi)
#pragma unroll
          for (int r = 0; r < 4; ++r) {
            int kg = t * 64 + mi * 16 + lg * 4 + r;
            if (kg <= qg) rs4[r] += exp2f(acc[mi][r]);
          }
      }
    }
    bar_lds();
  }
  float rs = (rs4[0] + rs4[1]) + (rs4[2] + rs4[3]);
  rs += __shfl_xor(rs, 16);
  rs += __shfl_xor(rs, 32);
  float li = -__log2f(rs);                  // p = exp2(logit2 + li)

  // -------- sweep 2: recompute, write normalized attn, accumulate PV --------
  facc4 acc2[5] = {};
  ldtK(0); ldtV(0); sttK(0); sttV(0);
  if (NT > 1) { ldtK(1); ldtV(1); }
  bar_lds();
  for (int t = 0; t < NT; ++t) {
    int cur = t & 1;
    if (t + 1 < NT) { sttK(cur ^ 1); sttV(cur ^ 1); }   // waits only tile-(t-2) stores
    if (t + 2 < NT) { ldtK(t + 2); ldtV(t + 2); }
    if (64 * t >= wq0 + 16) {               // wave fully masked: zeros
      f32x4 z = {0.f, 0.f, 0.f, 0.f};
#pragma unroll
      for (int mi = 0; mi < 4; ++mi)
        *(f32x4*)(attnb + (size_t)qg * S_ + t * 64 + mi * 16 + lg * 4) = z;
    } else {
      facc4 acc[4] = {};
#pragma unroll
      for (int mi = 0; mi < 4; ++mi)
#pragma unroll
        for (int kd = 0; kd < 3; ++kd) {
          frag8 af = *(const frag8*)((const char*)sK + cur * (64 * 104 * 2) +
                                     (mi * 16 + lm) * 208 + kd * 64 + lg * 16);
          acc[mi] = __builtin_amdgcn_mfma_f32_16x16x32_bf16(af, qf[kd], acc[mi], 0, 0, 0);
        }
      bool full = (64 * t + 63 <= wq0);
#pragma unroll
      for (int mi = 0; mi < 4; ++mi) {
        float p[4];
        if (full) {
#pragma unroll
          for (int r = 0; r < 4; ++r) p[r] = exp2f(acc[mi][r] + li);
        } else {
#pragma unroll
          for (int r = 0; r < 4; ++r) {
            int kg = t * 64 + mi * 16 + lg * 4 + r;
            p[r] = (kg <= qg) ? exp2f(acc[mi][r] + li) : 0.f;
          }
        }
        f32x4 f4 = {p[0], p[1], p[2], p[3]};
        *(f32x4*)(attnb + (size_t)qg * S_ + t * 64 + mi * 16 + lg * 4) = f4;
        uint2 pk;
        pk.x = cvt_pk(p[0], p[1]);
        pk.y = cvt_pk(p[2], p[3]);
        int kb = mi * 32 + lg * 8;
        *(uint2*)(Pw + lm * 128 + (kb ^ ((lm & 7) << 4))) = pk;  // wave-private, no barrier
      }
      // PV: P from wave-private LDS, V from staged LDS (no vmem on this path)
#pragma unroll
      for (int ks = 0; ks < 2; ++ks) {
        int kbyte = ks * 64 + lg * 16;
        frag8 pa = *(const frag8*)(Pw + lm * 128 + (kbyte ^ ((lm & 7) << 4)));
#pragma unroll
        for (int nf = 0; nf < 5; ++nf) {
          frag8 vb = *(const frag8*)&sV[cur][nf * 16 + lm][ks * 32 + lg * 8];
          acc2[nf] = __builtin_amdgcn_mfma_f32_16x16x32_bf16(pa, vb, acc2[nf], 0, 0, 0);
        }
      }
    }
    bar_lds();
  }
  // PV out: D col = d (lane&15), row = q_local = lg*4 + r
#pragma unroll
  for (int nf = 0; nf < 5; ++nf)
#pragma unroll
    for (int r = 0; r < 4; ++r) {
      int qrow = q0 + w * 16 + lg * 4 + r;
      int col = h * DH + nf * 16 + lm;
      outh[((size_t)b * S_ + qrow) * DM + col] = f2bf(acc2[nf][r]);
    }

  // -------- zero-fill strictly-masked column range [128*(s+1), 2048) — at the END --------
  if (s < 15) {
    int c0 = (s + 1) * 128;
    int r2 = tid >> 2;
    int l4 = (tid & 3) << 2;
    float* rowp = attnb + (size_t)(q0 + r2) * S_ + c0 + l4;
    f32x4 z = {0.f, 0.f, 0.f, 0.f};
    for (int cc = 0; cc < 2048 - c0; cc += 16)
      __builtin_nontemporal_store(z, (f32x4*)(rowp + cc));
  }
}

extern "C" void kernel_launch(void* const* d_in, const int* in_sizes, int n_in,
                              void* d_out, int out_size, void* d_ws, size_t ws_size,
                              hipStream_t stream) {
  const float* v  = (const float*)d_in[0];
  const float* k  = (const float*)d_in[1];
  const float* q  = (const float*)d_in[2];
  // d_in[3] = mask (exact causal triu) — applied analytically
  const float* wq = (const float*)d_in[4];
  const float* bq = (const float*)d_in[5];
  const float* wk = (const float*)d_in[6];
  const float* bk = (const float*)d_in[7];
  const float* wv = (const float*)d_in[8];
  const float* bv = (const float*)d_in[9];
  const float* wd = (const float*)d_in[10];
  const float* bd = (const float*)d_in[11];
  ushort_t* ws = (ushort_t*)d_ws;
  float* out  = (float*)d_out;            // [2,2048,1280] fp32
  float* attn = out + IN_E;               // [2,16,2048,2048] fp32

  convert_kernel<<<2048, 256, 0, stream>>>(wq, wk, wv, wd, ws);
  qkv_kernel<<<960, 256, 0, stream>>>(q, k, v, ws + OFF_WQ, bq, bk, bv,
                                      ws + OFF_QH, ws + OFF_KH, ws + OFF_VT);
  attn_kernel<<<512, 512, 0, stream>>>(ws + OFF_QH, ws + OFF_KH, ws + OFF_VT, ws + OFF_OH, attn);
  dense_kernel<<<320, 256, 0, stream>>>(ws + OFF_OH, ws + OFF_WD, bd, out);
}